// Round 8
// baseline (258.925 us; speedup 1.0000x reference)
//
#include <hip/hip_runtime.h>
#include <hip/hip_bf16.h>

// CausalSelfAttention: B=4, S=2048, D=1024, H=16, Dh=64. fp32 in/out, bf16 MFMA compute.
//
// Pipeline (all on `stream`):
//   1. convert_x: x fp32 -> bf16 (8192x1024)
//   2. transpose_w: Wq|Wk|Wv -> wqkvt (3072x1024 bf16, N-major), Wo -> wot
//   3. pack_bqkv: [bq|bk|bv] -> fp32 (3072)
//   4. gemm256 v5 (R18): faithful m201 8-phase port. 256^2, BK=64, 8 waves (2Mx4N),
//      per K-tile 4 phases, each {ds_reads; stage 1 half-tile; s_barrier; lgkmcnt(0);
//      setprio; 16 MFMA; setprio; s_barrier}. RAW barriers (no vmcnt drain); ONE
//      counted vmcnt(6) per K-tile at ph4 retires exactly the next tile's 4 units
//      (3 half-tiles stay in flight). Stage stagger: ph1->A1(t+1) [other buf],
//      ph2->B0(t+2), ph3->B1(t+2), ph4->A0(t+2) [current buf -- safe: B reads all
//      sealed at ph1's 2nd barrier (B front-loaded), A reads at ph2's].
//      R12 failed this structure only because of sched_barrier(0) over-pinning.
//   5. attn: flash attention (R11/R4 winner, exact revert: (256,2), no setprio --
//      R17's 3-blocks/CU + setprio was neutral-to-negative)
//   6. gemm_bt<1>: out = attn @ Wo + bo -> fp32 d_out (original unswizzled 128^2)

typedef __bf16 bf16x8 __attribute__((ext_vector_type(8)));
typedef float f32x4 __attribute__((ext_vector_type(4)));
typedef unsigned short u16;

__device__ __forceinline__ u16 f2b(float f) {
    __hip_bfloat16 h = __float2bfloat16(f);
    return __builtin_bit_cast(unsigned short, h);
}

__device__ __forceinline__ f32x4 mfma16(bf16x8 a, bf16x8 b, f32x4 c) {
    return __builtin_amdgcn_mfma_f32_16x16x32_bf16(a, b, c, 0, 0, 0);
}

typedef const __attribute__((address_space(1))) unsigned int* gas1_t;
typedef __attribute__((address_space(3))) unsigned int* las3_t;
// Async global->LDS, 16B/lane. LDS dest = wave-uniform base + lane*16 (m104/m108).
__device__ __forceinline__ void gld16(const void* g, void* l) {
    __builtin_amdgcn_global_load_lds((gas1_t)g, (las3_t)l, 16, 0, 0);
}

// ---------------------------------------------------------------- conversions
__global__ __launch_bounds__(256) void convert_x(const float* __restrict__ x,
                                                 u16* __restrict__ xb, int n4) {
    int i = blockIdx.x * 256 + threadIdx.x;
    if (i < n4) {
        float4 v = ((const float4*)x)[i];
        ushort4 u;
        u.x = f2b(v.x); u.y = f2b(v.y); u.z = f2b(v.z); u.w = f2b(v.w);
        ((ushort4*)xb)[i] = u;
    }
}

// W (K=1024 rows, N=1024 cols) fp32 -> Wt (N,K) bf16. z selects matrix.
__global__ __launch_bounds__(256) void transpose_w(const float* __restrict__ Wq,
                                                   const float* __restrict__ Wk,
                                                   const float* __restrict__ Wv,
                                                   const float* __restrict__ Wo,
                                                   u16* __restrict__ wqkvt,
                                                   u16* __restrict__ wot) {
    const int z = blockIdx.z;
    const float* src = (z == 0) ? Wq : (z == 1) ? Wk : (z == 2) ? Wv : Wo;
    u16* dst = (z == 3) ? wot : (wqkvt + (size_t)z * 1024 * 1024);
    __shared__ float tile[32][33];
    const int tx = threadIdx.x, ty = threadIdx.y;  // block (32,8)
    const int nbase = blockIdx.x * 32, kbase = blockIdx.y * 32;
    for (int j = 0; j < 4; ++j)
        tile[ty + j * 8][tx] = src[(size_t)(kbase + ty + j * 8) * 1024 + nbase + tx];
    __syncthreads();
    for (int j = 0; j < 4; ++j)
        dst[(size_t)(nbase + ty + j * 8) * 1024 + kbase + tx] = f2b(tile[tx][ty + j * 8]);
}

__global__ __launch_bounds__(256) void pack_bqkv(const float* __restrict__ bq,
                                                 const float* __restrict__ bk,
                                                 const float* __restrict__ bv,
                                                 float* __restrict__ bqkv) {
    int i = blockIdx.x * 256 + threadIdx.x;  // 3072 total
    bqkv[i] = (i < 1024) ? bq[i] : (i < 2048) ? bk[i - 1024] : bv[i - 2048];
}

// ---------------------------------------------------------------- GEMM 256^2 v5 (m201 port)
// C(M,N) = A(M,K) @ Bt(N,K)^T + bias, QKV epilogue. BM=BN=256, BK=64, 512 thr = 8 waves.
// Waves 2M x 4N: wave = 128 rows x 64 cols; acc[8][4] f32x4.
// LDS 128 KiB: As/Bs[2 dbuf][256 rows][64 u16], chunk^(row&7) swizzle (conflict-free).
// Phases per K-tile t (buf c=t&1, other n): quadrants (m0n0)(m1n0)(m1n1)(m0n1).
//   ph1: read aR0(8) + bR all(8); stage A1(t+1)->n;  bar lgkm0 prio MM bar
//   ph2: read aR1(8);             stage B0(t+2)->c;  bar lgkm0 prio MM bar
//   ph3:                          stage B1(t+2)->c;  bar       prio MM bar
//   ph4:                          stage A0(t+2)->c;  vmcnt(6) bar prio MM bar
// WAR safety: B-half reads all sealed at ph1 2nd barrier (B front-loaded); A-half
// reads sealed at ph2 2nd barrier -> t+2 stages into buf c at ph2/3/4 are race-free.
// vmcnt(6) math (2 loads/unit): prologue 7 units -> vmcnt(6) retires tile0's 4;
// steady state: at ph4 queue = [A1(t+1),B0,B1,A0(t+2)]=8 -> vmcnt(6) retires
// A1(t+1), i.e. ALL of tile t+1 resident before its ph1 reads. Never vmcnt(0).
__global__ __launch_bounds__(512, 1) void gemm256(const u16* __restrict__ A,
                                                  const u16* __restrict__ Bt,
                                                  const float* __restrict__ bias,
                                                  u16* __restrict__ qkout,
                                                  u16* __restrict__ vtout,
                                                  int K) {
    const int tid = threadIdx.x;
    const int l = tid & 63;
    const int w = tid >> 6;   // 0..7
    const int mw2 = w >> 2;   // 0..1: wave rows = mw2*128..+127
    const int nw4 = w & 3;    // 0..3: wave cols = nw4*64..+63
    const int tileM = blockIdx.x * 256;
    const int tileN = blockIdx.y * 256;

    __shared__ u16 As[2][256 * 64];  // [buf][row*64 + col], 128B rows
    __shared__ u16 Bs[2][256 * 64];

    // read-side swizzled chunk offsets (u16 units) per ks: ((ks*4+(l>>4)) ^ (l&7))*8
    const int co0 = (((l >> 4)) ^ (l & 7)) * 8;
    const int co1 = ((4 + (l >> 4)) ^ (l & 7)) * 8;
    const int mrow = l & 15;

    // stage-side per-lane global base: row offset (l>>3), chunk (l&7)^(l>>3)
    const int sro = l >> 3;
    const int scg = (l & 7) ^ sro;
    const u16* aSt = A + (size_t)(tileM + w * 16 + sro) * K + scg * 8;
    const u16* bSt = Bt + (size_t)(tileN + w * 16 + sro) * K + scg * 8;

    f32x4 acc[8][4] = {};
    bf16x8 aR0[4][2], aR1[4][2];  // m-half 0 / 1 frags (both live through ph4)
    bf16x8 bR[4][2];              // all 4 n-frags (front-loaded at ph1)

    // stage one 128-row half (mat: 0=A, 1=B) of K-tile tt into buf nb
    auto stage = [&](int mat, int h, int tt, int nb) {
        const size_t go = (size_t)h * 128 * K + (size_t)tt * 64;
        u16* lb = (mat ? &Bs[nb][0] : &As[nb][0]) + (h * 128 + w * 16) * 64;
        const u16* gp = (mat ? bSt : aSt) + go;
        gld16(gp, lb);
        gld16(gp + (size_t)8 * K, lb + 8 * 64);
    };
    auto loadA = [&](bf16x8 (&dst)[4][2], int mh, int buf) {
#pragma unroll
        for (int i = 0; i < 4; ++i) {
            const int r = mw2 * 128 + mh * 64 + i * 16 + mrow;
            dst[i][0] = *(const bf16x8*)&As[buf][r * 64 + co0];
            dst[i][1] = *(const bf16x8*)&As[buf][r * 64 + co1];
        }
    };
    auto loadB = [&](int nh, int buf) {
#pragma unroll
        for (int j = 0; j < 2; ++j) {
            const int r = nw4 * 64 + nh * 32 + j * 16 + mrow;
            bR[nh * 2 + j][0] = *(const bf16x8*)&Bs[buf][r * 64 + co0];
            bR[nh * 2 + j][1] = *(const bf16x8*)&Bs[buf][r * 64 + co1];
        }
    };
    // 16-MFMA quadrant: 4 m-frags (from aX) x 2 n-frags [j0,j0+1] x 2 ks
    auto mmq = [&](bf16x8 (&aX)[4][2], int i0, int j0) {
        __builtin_amdgcn_s_setprio(1);
#pragma unroll
        for (int ks = 0; ks < 2; ++ks)
#pragma unroll
            for (int i = 0; i < 4; ++i)
#pragma unroll
                for (int j = 0; j < 2; ++j)
                    acc[i0 + i][j0 + j] =
                        mfma16(aX[i][ks], bR[j0 + j][ks], acc[i0 + i][j0 + j]);
        __builtin_amdgcn_s_setprio(0);
    };

    // prologue: tile0 all 4 units + tile1 B0,B1,A0 (7 units); retire tile0
    stage(1, 0, 0, 0); stage(1, 1, 0, 0); stage(0, 0, 0, 0); stage(0, 1, 0, 0);
    stage(1, 0, 1, 1); stage(1, 1, 1, 1); stage(0, 0, 1, 1);
    asm volatile("s_waitcnt vmcnt(6)" ::: "memory");
    __builtin_amdgcn_s_barrier();

    const int NT = K >> 6;
    for (int t = 0; t < NT; ++t) {
        const int c = t & 1, n = c ^ 1;
        const int t1 = (t + 1 < NT) ? t + 1 : NT - 1;  // clamped dummy keeps counts
        const int t2 = (t + 2 < NT) ? t + 2 : NT - 1;

        // ph1: quadrant (m0,n0)
        loadA(aR0, 0, c);
        loadB(0, c);
        loadB(1, c);
        stage(0, 1, t1, n);  // A1(t+1)
        __builtin_amdgcn_s_barrier();
        asm volatile("s_waitcnt lgkmcnt(0)" ::: "memory");
        mmq(aR0, 0, 0);
        __builtin_amdgcn_s_barrier();

        // ph2: quadrant (m1,n0)
        loadA(aR1, 1, c);
        stage(1, 0, t2, c);  // B0(t+2) -- B reads sealed at ph1 2nd barrier
        __builtin_amdgcn_s_barrier();
        asm volatile("s_waitcnt lgkmcnt(0)" ::: "memory");
        mmq(aR1, 4, 0);
        __builtin_amdgcn_s_barrier();

        // ph3: quadrant (m1,n1)
        stage(1, 1, t2, c);  // B1(t+2)
        __builtin_amdgcn_s_barrier();
        mmq(aR1, 4, 2);
        __builtin_amdgcn_s_barrier();

        // ph4: quadrant (m0,n1)
        stage(0, 0, t2, c);  // A0(t+2) -- A reads sealed at ph2 2nd barrier
        asm volatile("s_waitcnt vmcnt(6)" ::: "memory");  // retires ALL of tile t+1
        __builtin_amdgcn_s_barrier();
        mmq(aR0, 0, 2);
        __builtin_amdgcn_s_barrier();
    }

    // epilogue. C/D layout: row=(l>>4)*4+r, col=l&15 [m89/m91].
    // tileN granularity 256 => whole block uniformly Q (<1024), K (<2048) or V.
    const int rbase = (l >> 4) * 4;
#pragma unroll
    for (int i = 0; i < 8; ++i) {
#pragma unroll
        for (int j = 0; j < 4; ++j) {
            const int gm0 = tileM + mw2 * 128 + i * 16 + rbase;
            const int gn = tileN + nw4 * 64 + j * 16 + (l & 15);
            const float bv_ = bias[gn];
            const f32x4 a = acc[i][j];
            if (tileN < 2048) {
                // fold softmax scale * log2e into Q
                const float qs = (tileN < 1024) ? 0.125f * 1.4426950408889634f : 1.0f;
#pragma unroll
                for (int r = 0; r < 4; ++r)
                    qkout[(size_t)(gm0 + r) * 2048 + gn] = f2b((a[r] + bv_) * qs);
            } else {
                const int b = gm0 >> 11, s0 = gm0 & 2047;
                const int gn2 = gn - 2048;
                const int h = gn2 >> 6, dh = gn2 & 63;
                ushort4 u;
                u.x = f2b(a[0] + bv_); u.y = f2b(a[1] + bv_);
                u.z = f2b(a[2] + bv_); u.w = f2b(a[3] + bv_);
                *(ushort4*)&vtout[((size_t)((b * 16 + h) * 64 + dh)) * 2048 + s0] = u;
            }
        }
    }
}

// ---------------------------------------------------------------- GEMM (original 128^2)
// C(M,N) = A(M,K) @ Bt(N,K)^T + bias. 128x128 tile, BK=32, 256 thr = 4 waves.
// Used for MODE 1 (output projection) only. Unswizzled (R16: swizzle regressed).
template <int MODE>
__global__ __launch_bounds__(256, 2) void gemm_bt(const u16* __restrict__ A,
                                                  const u16* __restrict__ Bt,
                                                  const float* __restrict__ bias,
                                                  void* __restrict__ Cout,
                                                  void* __restrict__ Cout2,
                                                  int M, int N, int K, int ldc) {
    const int tid = threadIdx.x;
    const int l = tid & 63;
    const int w = tid >> 6;
    const int tileM = blockIdx.x * 128;
    const int tileN = blockIdx.y * 128;

    __shared__ u16 As[2][128 * 32];  // [buf][row][k] stride 32
    __shared__ u16 Bs[2][128 * 32];

    const int srow = l >> 2;
    const int schunk = l & 3;
    const int mrow = l & 15;
    const int g8 = (l >> 4) * 8;
    const int waveM = (w & 1) * 64;
    const int waveN = (w >> 1) * 64;

    const u16* a0 = A + (size_t)(tileM + w * 32 + srow) * K + schunk * 8;
    const u16* a1 = A + (size_t)(tileM + w * 32 + 16 + srow) * K + schunk * 8;
    const u16* b0 = Bt + (size_t)(tileN + w * 32 + srow) * K + schunk * 8;
    const u16* b1 = Bt + (size_t)(tileN + w * 32 + 16 + srow) * K + schunk * 8;

    f32x4 acc[4][4] = {};

    gld16(a0, &As[0][(w * 2) * 512]);
    gld16(a1, &As[0][(w * 2 + 1) * 512]);
    gld16(b0, &Bs[0][(w * 2) * 512]);
    gld16(b1, &Bs[0][(w * 2 + 1) * 512]);
    __syncthreads();

    for (int k0 = 0; k0 < K; k0 += 32) {
        const int cur = (k0 >> 5) & 1;
        if (k0 + 32 < K) {
            const int nb = cur ^ 1;
            gld16(a0 + k0 + 32, &As[nb][(w * 2) * 512]);
            gld16(a1 + k0 + 32, &As[nb][(w * 2 + 1) * 512]);
            gld16(b0 + k0 + 32, &Bs[nb][(w * 2) * 512]);
            gld16(b1 + k0 + 32, &Bs[nb][(w * 2 + 1) * 512]);
        }

        bf16x8 af[4], bf[4];
        for (int im = 0; im < 4; ++im)
            af[im] = *(const bf16x8*)&As[cur][(waveM + im * 16 + mrow) * 32 + g8];
        for (int in = 0; in < 4; ++in)
            bf[in] = *(const bf16x8*)&Bs[cur][(waveN + in * 16 + mrow) * 32 + g8];
        for (int im = 0; im < 4; ++im)
            for (int in = 0; in < 4; ++in)
                acc[im][in] = mfma16(af[im], bf[in], acc[im][in]);
        __syncthreads();
    }

    const int rbase = (l >> 4) * 4;
    for (int im = 0; im < 4; ++im) {
        for (int in = 0; in < 4; ++in) {
            const int gm0 = tileM + waveM + im * 16 + rbase;
            const int gn = tileN + waveN + in * 16 + (l & 15);
            const float bv_ = bias[gn];
            if (MODE == 1) {
                float* out = (float*)Cout;
                for (int r = 0; r < 4; ++r)
                    out[(size_t)(gm0 + r) * ldc + gn] = acc[im][in][r] + bv_;
            } else if (tileN < 2048) {
                const float qs = (tileN < 1024) ? 0.125f * 1.4426950408889634f : 1.0f;
                u16* out = (u16*)Cout;
                for (int r = 0; r < 4; ++r)
                    out[(size_t)(gm0 + r) * 2048 + gn] = f2b((acc[im][in][r] + bv_) * qs);
            } else {
                u16* out = (u16*)Cout2;
                const int b = gm0 >> 11, s0 = gm0 & 2047;
                const int gn2 = gn - 2048;
                const int h = gn2 >> 6, dh = gn2 & 63;
                ushort4 u;
                u.x = f2b(acc[im][in][0] + bv_);
                u.y = f2b(acc[im][in][1] + bv_);
                u.z = f2b(acc[im][in][2] + bv_);
                u.w = f2b(acc[im][in][3] + bv_);
                *(ushort4*)&out[((size_t)((b * 16 + h) * 64 + dh)) * 2048 + s0] = u;
            }
        }
    }
}

// ---------------------------------------------------------------- flash attention
// R11/R4 winner, exact: 256 thr = 4 waves, 2 blocks/CU, 128 queries/block, ONE
// barrier/round, K/V staged by global_load_lds DMA into double-buffered
// XOR-swizzled LDS tiles, max-free softmax with epilogue-only denominator.
__global__ __launch_bounds__(256, 2) void attn_kernel(const u16* __restrict__ qk,
                                                      const u16* __restrict__ vt,
                                                      u16* __restrict__ attn) {
    const int bh = blockIdx.x;
    const int qt = 15 - (int)blockIdx.y;  // big q-tiles launch first
    const int b = bh >> 4, h = bh & 15;
    const int q0 = qt * 128;
    const int tid = threadIdx.x, l = tid & 63, w = tid >> 6;
    const int q = l & 15;   // query column within group
    const int g = l >> 4;   // k-group
    const int g8 = g * 8;

    __shared__ u16 Ks[2][64 * 64];  // [buf][key][dh]   XOR-swizzled chunks
    __shared__ u16 Vs[2][64 * 64];  // [buf][dh][key]   XOR-swizzled chunks
    __shared__ u16 Ps[128 * 72];    // Q staging, then per-wave P slabs [query][key]

    const int sr8 = l >> 3;
    const int gc = (l & 7) ^ sr8;
    const u16* kgl = qk + (size_t)(b * 2048 + w * 16 + sr8) * 2048 + 1024 + h * 64 + gc * 8;
    const u16* vgl = vt + (size_t)(bh * 64 + w * 16 + sr8) * 2048 + gc * 8;

    for (int i = 0; i < 4; ++i) {
        const int idx = i * 256 + tid;
        const int row = idx >> 3, ch = idx & 7;
        *(uint4*)&Ps[row * 72 + ch * 8] =
            *(const uint4*)&qk[(size_t)(b * 2048 + q0 + row) * 2048 + h * 64 + ch * 8];
    }
    for (int j = 0; j < 2; ++j) {
        gld16(kgl + (size_t)(j * 8) * 2048, &Ks[0][(w * 16 + j * 8) * 64]);
        gld16(vgl + (size_t)(j * 8) * 2048, &Vs[0][(w * 16 + j * 8) * 64]);
    }
    __syncthreads();

    bf16x8 qb[2][2];
    for (int c = 0; c < 2; ++c) {
        qb[c][0] = *(const bf16x8*)&Ps[(w * 32 + c * 16 + q) * 72 + g8];
        qb[c][1] = *(const bf16x8*)&Ps[(w * 32 + c * 16 + q) * 72 + 32 + g8];
    }

    const int cl0 = ((g) ^ (q & 7)) * 8;
    const int cl1 = ((4 + g) ^ (q & 7)) * 8;

    float li[2] = {0.f, 0.f};
    f32x4 o[2][4] = {};
    const int tmax = 2 * qt + 1;
    const int tdiag = (q0 + w * 32 + 31) >> 6;

    for (int t = 0; t <= tmax; ++t) {
        const int tp = (t < tmax) ? t + 1 : tmax;
        const int nb = (t + 1) & 1;
        for (int j = 0; j < 2; ++j) {
            gld16(kgl + (size_t)(tp * 64 + j * 8) * 2048, &Ks[nb][(w * 16 + j * 8) * 64]);
            gld16(vgl + (size_t)(j * 8) * 2048 + tp * 64, &Vs[nb][(w * 16 + j * 8) * 64]);
        }

        if (t <= tdiag) {
            const int cb0 = t & 1;
            const int kv0 = t * 64;
            const u16* ks = &Ks[cb0][0];
            const u16* vs = &Vs[cb0][0];

            f32x4 st[2][4] = {};
            for (int cb = 0; cb < 4; ++cb) {
                bf16x8 ka0 = *(const bf16x8*)&ks[(cb * 16 + q) * 64 + cl0];
                bf16x8 ka1 = *(const bf16x8*)&ks[(cb * 16 + q) * 64 + cl1];
                st[0][cb] = mfma16(ka0, qb[0][0], st[0][cb]);
                st[1][cb] = mfma16(ka0, qb[1][0], st[1][cb]);
                st[0][cb] = mfma16(ka1, qb[0][1], st[0][cb]);
                st[1][cb] = mfma16(ka1, qb[1][1], st[1][cb]);
            }
            for (int c = 0; c < 2; ++c) {
                if (t == tdiag) {
                    const int qg = q0 + w * 32 + c * 16 + q;
                    for (int cb = 0; cb < 4; ++cb)
                        for (int r = 0; r < 4; ++r) {
                            const int key = kv0 + cb * 16 + g * 4 + r;
                            if (key > qg) st[c][cb][r] = -1e30f;
                        }
                }
                float ps = 0.f;
                for (int cb = 0; cb < 4; ++cb)
                    for (int r = 0; r < 4; ++r) {
                        const float p = __builtin_amdgcn_exp2f(st[c][cb][r]);
                        st[c][cb][r] = p;
                        ps += p;
                    }
                li[c] += ps;
                for (int cb = 0; cb < 4; ++cb) {
                    ushort4 u;
                    u.x = f2b(st[c][cb][0]); u.y = f2b(st[c][cb][1]);
                    u.z = f2b(st[c][cb][2]); u.w = f2b(st[c][cb][3]);
                    *(ushort4*)&Ps[(w * 32 + c * 16 + q) * 72 + cb * 16 + g * 4] = u;
                }
            }
            __builtin_amdgcn_s_waitcnt(0xC07F);  // lgkmcnt(0); DS in-order per wave
            for (int cb = 0; cb < 4; ++cb) {
                bf16x8 va0 = *(const bf16x8*)&vs[(cb * 16 + q) * 64 + cl0];
                bf16x8 va1 = *(const bf16x8*)&vs[(cb * 16 + q) * 64 + cl1];
                bf16x8 pb00 = *(const bf16x8*)&Ps[(w * 32 + q) * 72 + g8];
                bf16x8 pb01 = *(const bf16x8*)&Ps[(w * 32 + q) * 72 + 32 + g8];
                bf16x8 pb10 = *(const bf16x8*)&Ps[(w * 32 + 16 + q) * 72 + g8];
                bf16x8 pb11 = *(const bf16x8*)&Ps[(w * 32 + 16 + q) * 72 + 32 + g8];
                o[0][cb] = mfma16(va0, pb00, o[0][cb]);
                o[1][cb] = mfma16(va0, pb10, o[1][cb]);
                o[0][cb] = mfma16(va1, pb01, o[0][cb]);
                o[1][cb] = mfma16(va1, pb11, o[1][cb]);
            }
        }
        __syncthreads();
    }

    for (int c = 0; c < 2; ++c) {
        float ps = li[c];
        ps += __shfl_xor(ps, 16);
        ps += __shfl_xor(ps, 32);
        const float inv = 1.0f / ps;
        const size_t tok = (size_t)(b * 2048 + q0 + w * 32 + c * 16 + q);
        for (int cb = 0; cb < 4; ++cb) {
            ushort4 u;
            u.x = f2b(o[c][cb][0] * inv); u.y = f2b(o[c][cb][1] * inv);
            u.z = f2b(o[c][cb][2] * inv); u.w = f2b(o[c][cb][3] * inv);
            *(ushort4*)&attn[tok * 1024 + h * 64 + cb * 16 + g * 4] = u;
        }
    }
}

// ---------------------------------------------------------------- launch
extern "C" void kernel_launch(void* const* d_in, const int* in_sizes, int n_in,
                              void* d_out, int out_size, void* d_ws, size_t ws_size,
                              hipStream_t stream) {
    const float* x  = (const float*)d_in[0];
    const float* Wq = (const float*)d_in[1];
    const float* bq = (const float*)d_in[2];
    const float* Wk = (const float*)d_in[3];
    const float* bk = (const float*)d_in[4];
    const float* Wv = (const float*)d_in[5];
    const float* bv = (const float*)d_in[6];
    const float* Wo = (const float*)d_in[7];
    const float* bo = (const float*)d_in[8];
    float* out = (float*)d_out;

    char* ws = (char*)d_ws;
    size_t off = 0;
    auto alloc = [&](size_t bytes) -> void* {
        void* p = ws + off;
        off += (bytes + 255) & ~(size_t)255;
        return p;
    };
    u16*   xb    = (u16*)alloc(8192ull * 1024 * 2);   // x bf16
    u16*   wqkvt = (u16*)alloc(3072ull * 1024 * 2);   // [Wq|Wk|Wv]^T (N,K)
    u16*   wot   = (u16*)alloc(1024ull * 1024 * 2);   // Wo^T
    float* bqkv  = (float*)alloc(3072ull * 4);
    u16*   qk    = (u16*)alloc(8192ull * 2048 * 2);   // [q|k] (token, 2048)
    u16*   vt    = (u16*)alloc(8192ull * 1024 * 2);   // V^T (B,H,Dh,S)
    u16*   attn  = (u16*)alloc(8192ull * 1024 * 2);   // attention out (token, D)

    convert_x<<<8192, 256, 0, stream>>>(x, xb, 8192 * 1024 / 4);
    transpose_w<<<dim3(32, 32, 4), dim3(32, 8), 0, stream>>>(Wq, Wk, Wv, Wo, wqkvt, wot);
    pack_bqkv<<<12, 256, 0, stream>>>(bq, bk, bv, bqkv);
    gemm256<<<dim3(32, 12), 512, 0, stream>>>(xb, wqkvt, bqkv, qk, vt, 1024);
    attn_kernel<<<dim3(64, 16), 256, 0, stream>>>(qk, vt, attn);
    gemm_bt<1><<<dim3(64, 8), 256, 0, stream>>>(attn, wot, bo, out, nullptr, 8192, 1024, 1024, 1024);
}

// Round 9
// 237.166 us; speedup vs baseline: 1.0917x; 1.0917x over previous
//
#include <hip/hip_runtime.h>
#include <hip/hip_bf16.h>

// CausalSelfAttention: B=4, S=2048, D=1024, H=16, Dh=64. fp32 in/out, bf16 MFMA compute.
//
// Pipeline (all on `stream`):
//   1. convert_x: x fp32 -> bf16 (8192x1024)
//   2. transpose_w: Wq|Wk|Wv -> wqkvt (3072x1024 bf16, N-major), Wo -> wot
//   3. pack_bqkv: [bq|bk|bv] -> fp32 (3072)
//   4. gemm256 v6 (R19): v4's schedule (ONE __syncthreads/K-tile, skewed quadrant
//      phases -- best of 4 schedules tried: 71.7us) with BN 256->192.
//      Grid 32x16 = 512 blocks = EXACTLY 2 per CU (v4's 384 blocks left the 2nd
//      scheduling wave at 50% CU occupancy -> 75% avg utilization; this is the
//      pure tail-math fix, not another schedule experiment). LDS 112KB, 1 res.
//      Tiles straddle Q/K/V boundaries -> per-fragment epilogue routing.
//   5. attn: flash attention (R11/R4 winner, exact)
//   6. gemm_bt<1>: out = attn @ Wo + bo -> fp32 d_out (original unswizzled 128^2)

typedef __bf16 bf16x8 __attribute__((ext_vector_type(8)));
typedef float f32x4 __attribute__((ext_vector_type(4)));
typedef unsigned short u16;

__device__ __forceinline__ u16 f2b(float f) {
    __hip_bfloat16 h = __float2bfloat16(f);
    return __builtin_bit_cast(unsigned short, h);
}

__device__ __forceinline__ f32x4 mfma16(bf16x8 a, bf16x8 b, f32x4 c) {
    return __builtin_amdgcn_mfma_f32_16x16x32_bf16(a, b, c, 0, 0, 0);
}

typedef const __attribute__((address_space(1))) unsigned int* gas1_t;
typedef __attribute__((address_space(3))) unsigned int* las3_t;
// Async global->LDS, 16B/lane. LDS dest = wave-uniform base + lane*16 (m104/m108).
__device__ __forceinline__ void gld16(const void* g, void* l) {
    __builtin_amdgcn_global_load_lds((gas1_t)g, (las3_t)l, 16, 0, 0);
}

// ---------------------------------------------------------------- conversions
__global__ __launch_bounds__(256) void convert_x(const float* __restrict__ x,
                                                 u16* __restrict__ xb, int n4) {
    int i = blockIdx.x * 256 + threadIdx.x;
    if (i < n4) {
        float4 v = ((const float4*)x)[i];
        ushort4 u;
        u.x = f2b(v.x); u.y = f2b(v.y); u.z = f2b(v.z); u.w = f2b(v.w);
        ((ushort4*)xb)[i] = u;
    }
}

// W (K=1024 rows, N=1024 cols) fp32 -> Wt (N,K) bf16. z selects matrix.
__global__ __launch_bounds__(256) void transpose_w(const float* __restrict__ Wq,
                                                   const float* __restrict__ Wk,
                                                   const float* __restrict__ Wv,
                                                   const float* __restrict__ Wo,
                                                   u16* __restrict__ wqkvt,
                                                   u16* __restrict__ wot) {
    const int z = blockIdx.z;
    const float* src = (z == 0) ? Wq : (z == 1) ? Wk : (z == 2) ? Wv : Wo;
    u16* dst = (z == 3) ? wot : (wqkvt + (size_t)z * 1024 * 1024);
    __shared__ float tile[32][33];
    const int tx = threadIdx.x, ty = threadIdx.y;  // block (32,8)
    const int nbase = blockIdx.x * 32, kbase = blockIdx.y * 32;
    for (int j = 0; j < 4; ++j)
        tile[ty + j * 8][tx] = src[(size_t)(kbase + ty + j * 8) * 1024 + nbase + tx];
    __syncthreads();
    for (int j = 0; j < 4; ++j)
        dst[(size_t)(nbase + ty + j * 8) * 1024 + kbase + tx] = f2b(tile[tx][ty + j * 8]);
}

__global__ __launch_bounds__(256) void pack_bqkv(const float* __restrict__ bq,
                                                 const float* __restrict__ bk,
                                                 const float* __restrict__ bv,
                                                 float* __restrict__ bqkv) {
    int i = blockIdx.x * 256 + threadIdx.x;  // 3072 total
    bqkv[i] = (i < 1024) ? bq[i] : (i < 2048) ? bk[i - 1024] : bv[i - 2048];
}

// ---------------------------------------------------------------- GEMM 256x192 v6
// C(M,N) = A(M,K) @ Bt(N,K)^T + bias, QKV epilogue. BM=256, BN=192, BK=64,
// 512 thr = 8 waves (2M x 4N): wave = 128 rows x 48 cols; acc[8][3] f32x4.
// LDS 112 KiB: As[2][256][64], Bs[2][192][64]; rows 128B; chunk^(row&7) swizzle
// (conflict-free; all frag/stage rows are == mrow/l>>3 mod 8 since 48%8==0).
// Schedule = v4's winner: ONE __syncthreads per K-tile (implicit vmcnt drain;
// stages of t+1 issued during t's phases target the other buffer -> race-free);
// 4 skewed quadrant phases, no explicit waits, compiler per-wave lgkmcnt.
// Stage units of t+1: q0->A-h0 (2 gld16), q1->A-h1 (2), q2->B rows 0-127 (2),
// q3->B rows 128-191 (1 gld16: 8 waves x 8 rows).
__global__ __launch_bounds__(512, 2) void gemm256(const u16* __restrict__ A,
                                                  const u16* __restrict__ Bt,
                                                  const float* __restrict__ bias,
                                                  u16* __restrict__ qkout,
                                                  u16* __restrict__ vtout,
                                                  int K) {
    const int tid = threadIdx.x;
    const int l = tid & 63;
    const int w = tid >> 6;   // 0..7
    const int mw2 = w >> 2;   // 0..1: wave rows = mw2*128..+127
    const int nw4 = w & 3;    // 0..3: wave cols = nw4*48..+47
    const int tileM = blockIdx.x * 256;
    const int tileN = blockIdx.y * 192;

    __shared__ u16 As[2][256 * 64];  // [buf][row*64 + col], 128B rows
    __shared__ u16 Bs[2][192 * 64];

    // read-side swizzled chunk offsets (u16 units) per ks: ((ks*4+(l>>4)) ^ (l&7))*8
    const int co0 = (((l >> 4)) ^ (l & 7)) * 8;
    const int co1 = ((4 + (l >> 4)) ^ (l & 7)) * 8;
    const int mrow = l & 15;

    // stage-side per-lane global base: row offset (l>>3), chunk (l&7)^(l>>3)
    const int sro = l >> 3;
    const int scg = (l & 7) ^ sro;
    const u16* aSt = A + (size_t)(tileM + w * 16 + sro) * K + scg * 8;
    const u16* bSt = Bt + (size_t)(tileN + w * 16 + sro) * K + scg * 8;
    const u16* bSt1 = Bt + (size_t)(tileN + 128 + w * 8 + sro) * K + scg * 8;

    f32x4 acc[8][3] = {};
    bf16x8 aR[4][2];  // current m-half: 4 m-frags x 2 ks
    bf16x8 bR[3][2];  // all 3 n-frags x 2 ks

    auto stageA = [&](int h, int tt, int nb) {
        const u16* gp = aSt + (size_t)h * 128 * K + (size_t)tt * 64;
        u16* lb = &As[nb][(h * 128 + w * 16) * 64];
        gld16(gp, lb);
        gld16(gp + (size_t)8 * K, lb + 8 * 64);
    };
    auto stageB0 = [&](int tt, int nb) {  // B rows 0..127
        const u16* gp = bSt + (size_t)tt * 64;
        u16* lb = &Bs[nb][(w * 16) * 64];
        gld16(gp, lb);
        gld16(gp + (size_t)8 * K, lb + 8 * 64);
    };
    auto stageB1 = [&](int tt, int nb) {  // B rows 128..191: 8 waves x 8 rows
        gld16(bSt1 + (size_t)tt * 64, &Bs[nb][(128 + w * 8) * 64]);
    };
    auto loadA = [&](int mh, int buf) {
#pragma unroll
        for (int i = 0; i < 4; ++i) {
            const int r = mw2 * 128 + mh * 64 + i * 16 + mrow;
            aR[i][0] = *(const bf16x8*)&As[buf][r * 64 + co0];
            aR[i][1] = *(const bf16x8*)&As[buf][r * 64 + co1];
        }
    };
    auto loadB01 = [&](int buf) {
#pragma unroll
        for (int j = 0; j < 2; ++j) {
            const int r = nw4 * 48 + j * 16 + mrow;
            bR[j][0] = *(const bf16x8*)&Bs[buf][r * 64 + co0];
            bR[j][1] = *(const bf16x8*)&Bs[buf][r * 64 + co1];
        }
    };
    auto loadB2 = [&](int buf) {
        const int r = nw4 * 48 + 32 + mrow;
        bR[2][0] = *(const bf16x8*)&Bs[buf][r * 64 + co0];
        bR[2][1] = *(const bf16x8*)&Bs[buf][r * 64 + co1];
    };
    // MFMA cluster: m-frags [mi0..mi0+3] x n-frags [j0..j0+jn-1] x 2 ks
    auto mm = [&](int mi0, int j0, int jn) {
        __builtin_amdgcn_s_setprio(1);
#pragma unroll
        for (int ks = 0; ks < 2; ++ks)
#pragma unroll
            for (int i = 0; i < 4; ++i)
                for (int j = j0; j < j0 + jn; ++j)
                    acc[mi0 + i][j] = mfma16(aR[i][ks], bR[j][ks], acc[mi0 + i][j]);
        __builtin_amdgcn_s_setprio(0);
    };

    // prologue: all units of tile 0 into buf 0
    stageA(0, 0, 0); stageA(1, 0, 0); stageB0(0, 0); stageB1(0, 0);

    const int NT = K >> 6;
    for (int t = 0; t < NT; ++t) {
        const int buf = t & 1, nb = buf ^ 1;
        const bool pf = (t + 1 < NT);
        __syncthreads();  // implicit vmcnt(0)+lgkmcnt(0): this tile's units resident

        // q0: (m0, n frags 0-1)   reads 12, stage A-h0(t+1)
        loadA(0, buf);
        loadB01(buf);
        if (pf) stageA(0, t + 1, nb);
        mm(0, 0, 2);
        // q1: (m0, n frag 2)      reads 2, stage A-h1(t+1)
        loadB2(buf);
        if (pf) stageA(1, t + 1, nb);
        mm(0, 2, 1);
        // q2: (m1, n frag 2)      reads 8, stage B rows 0-127 (t+1)
        loadA(1, buf);
        if (pf) stageB0(t + 1, nb);
        mm(4, 2, 1);
        // q3: (m1, n frags 0-1)   reads 0, stage B rows 128-191 (t+1)
        if (pf) stageB1(t + 1, nb);
        mm(4, 0, 2);
    }

    // epilogue. C/D layout: row=(l>>4)*4+r, col=l&15 [m89/m91].
    // BN=192 tiles straddle the 1024/2048 boundaries -> route per fragment
    // (16-col fragments never straddle: boundaries are multiples of 16).
    const int rbase = (l >> 4) * 4;
#pragma unroll
    for (int i = 0; i < 8; ++i) {
#pragma unroll
        for (int j = 0; j < 3; ++j) {
            const int gm0 = tileM + mw2 * 128 + i * 16 + rbase;
            const int gn = tileN + nw4 * 48 + j * 16 + (l & 15);
            const float bv_ = bias[gn];
            const f32x4 a = acc[i][j];
            if (gn < 2048) {
                // fold softmax scale * log2e into Q
                const float qs = (gn < 1024) ? 0.125f * 1.4426950408889634f : 1.0f;
#pragma unroll
                for (int r = 0; r < 4; ++r)
                    qkout[(size_t)(gm0 + r) * 2048 + gn] = f2b((a[r] + bv_) * qs);
            } else {
                const int b = gm0 >> 11, s0 = gm0 & 2047;
                const int gn2 = gn - 2048;
                const int h = gn2 >> 6, dh = gn2 & 63;
                ushort4 u;
                u.x = f2b(a[0] + bv_); u.y = f2b(a[1] + bv_);
                u.z = f2b(a[2] + bv_); u.w = f2b(a[3] + bv_);
                *(ushort4*)&vtout[((size_t)((b * 16 + h) * 64 + dh)) * 2048 + s0] = u;
            }
        }
    }
}

// ---------------------------------------------------------------- GEMM (original 128^2)
// C(M,N) = A(M,K) @ Bt(N,K)^T + bias. 128x128 tile, BK=32, 256 thr = 4 waves.
// Used for MODE 1 (output projection) only. Unswizzled (R16: swizzle regressed).
template <int MODE>
__global__ __launch_bounds__(256, 2) void gemm_bt(const u16* __restrict__ A,
                                                  const u16* __restrict__ Bt,
                                                  const float* __restrict__ bias,
                                                  void* __restrict__ Cout,
                                                  void* __restrict__ Cout2,
                                                  int M, int N, int K, int ldc) {
    const int tid = threadIdx.x;
    const int l = tid & 63;
    const int w = tid >> 6;
    const int tileM = blockIdx.x * 128;
    const int tileN = blockIdx.y * 128;

    __shared__ u16 As[2][128 * 32];  // [buf][row][k] stride 32
    __shared__ u16 Bs[2][128 * 32];

    const int srow = l >> 2;
    const int schunk = l & 3;
    const int mrow = l & 15;
    const int g8 = (l >> 4) * 8;
    const int waveM = (w & 1) * 64;
    const int waveN = (w >> 1) * 64;

    const u16* a0 = A + (size_t)(tileM + w * 32 + srow) * K + schunk * 8;
    const u16* a1 = A + (size_t)(tileM + w * 32 + 16 + srow) * K + schunk * 8;
    const u16* b0 = Bt + (size_t)(tileN + w * 32 + srow) * K + schunk * 8;
    const u16* b1 = Bt + (size_t)(tileN + w * 32 + 16 + srow) * K + schunk * 8;

    f32x4 acc[4][4] = {};

    gld16(a0, &As[0][(w * 2) * 512]);
    gld16(a1, &As[0][(w * 2 + 1) * 512]);
    gld16(b0, &Bs[0][(w * 2) * 512]);
    gld16(b1, &Bs[0][(w * 2 + 1) * 512]);
    __syncthreads();

    for (int k0 = 0; k0 < K; k0 += 32) {
        const int cur = (k0 >> 5) & 1;
        if (k0 + 32 < K) {
            const int nb = cur ^ 1;
            gld16(a0 + k0 + 32, &As[nb][(w * 2) * 512]);
            gld16(a1 + k0 + 32, &As[nb][(w * 2 + 1) * 512]);
            gld16(b0 + k0 + 32, &Bs[nb][(w * 2) * 512]);
            gld16(b1 + k0 + 32, &Bs[nb][(w * 2 + 1) * 512]);
        }

        bf16x8 af[4], bf[4];
        for (int im = 0; im < 4; ++im)
            af[im] = *(const bf16x8*)&As[cur][(waveM + im * 16 + mrow) * 32 + g8];
        for (int in = 0; in < 4; ++in)
            bf[in] = *(const bf16x8*)&Bs[cur][(waveN + in * 16 + mrow) * 32 + g8];
        for (int im = 0; im < 4; ++im)
            for (int in = 0; in < 4; ++in)
                acc[im][in] = mfma16(af[im], bf[in], acc[im][in]);
        __syncthreads();
    }

    const int rbase = (l >> 4) * 4;
    for (int im = 0; im < 4; ++im) {
        for (int in = 0; in < 4; ++in) {
            const int gm0 = tileM + waveM + im * 16 + rbase;
            const int gn = tileN + waveN + in * 16 + (l & 15);
            const float bv_ = bias[gn];
            if (MODE == 1) {
                float* out = (float*)Cout;
                for (int r = 0; r < 4; ++r)
                    out[(size_t)(gm0 + r) * ldc + gn] = acc[im][in][r] + bv_;
            } else if (tileN < 2048) {
                const float qs = (tileN < 1024) ? 0.125f * 1.4426950408889634f : 1.0f;
                u16* out = (u16*)Cout;
                for (int r = 0; r < 4; ++r)
                    out[(size_t)(gm0 + r) * 2048 + gn] = f2b((acc[im][in][r] + bv_) * qs);
            } else {
                u16* out = (u16*)Cout2;
                const int b = gm0 >> 11, s0 = gm0 & 2047;
                const int gn2 = gn - 2048;
                const int h = gn2 >> 6, dh = gn2 & 63;
                ushort4 u;
                u.x = f2b(acc[im][in][0] + bv_);
                u.y = f2b(acc[im][in][1] + bv_);
                u.z = f2b(acc[im][in][2] + bv_);
                u.w = f2b(acc[im][in][3] + bv_);
                *(ushort4*)&out[((size_t)((b * 16 + h) * 64 + dh)) * 2048 + s0] = u;
            }
        }
    }
}

// ---------------------------------------------------------------- flash attention
// R11/R4 winner, exact: 256 thr = 4 waves, 2 blocks/CU, 128 queries/block, ONE
// barrier/round, K/V staged by global_load_lds DMA into double-buffered
// XOR-swizzled LDS tiles, max-free softmax with epilogue-only denominator.
__global__ __launch_bounds__(256, 2) void attn_kernel(const u16* __restrict__ qk,
                                                      const u16* __restrict__ vt,
                                                      u16* __restrict__ attn) {
    const int bh = blockIdx.x;
    const int qt = 15 - (int)blockIdx.y;  // big q-tiles launch first
    const int b = bh >> 4, h = bh & 15;
    const int q0 = qt * 128;
    const int tid = threadIdx.x, l = tid & 63, w = tid >> 6;
    const int q = l & 15;   // query column within group
    const int g = l >> 4;   // k-group
    const int g8 = g * 8;

    __shared__ u16 Ks[2][64 * 64];  // [buf][key][dh]   XOR-swizzled chunks
    __shared__ u16 Vs[2][64 * 64];  // [buf][dh][key]   XOR-swizzled chunks
    __shared__ u16 Ps[128 * 72];    // Q staging, then per-wave P slabs [query][key]

    const int sr8 = l >> 3;
    const int gc = (l & 7) ^ sr8;
    const u16* kgl = qk + (size_t)(b * 2048 + w * 16 + sr8) * 2048 + 1024 + h * 64 + gc * 8;
    const u16* vgl = vt + (size_t)(bh * 64 + w * 16 + sr8) * 2048 + gc * 8;

    for (int i = 0; i < 4; ++i) {
        const int idx = i * 256 + tid;
        const int row = idx >> 3, ch = idx & 7;
        *(uint4*)&Ps[row * 72 + ch * 8] =
            *(const uint4*)&qk[(size_t)(b * 2048 + q0 + row) * 2048 + h * 64 + ch * 8];
    }
    for (int j = 0; j < 2; ++j) {
        gld16(kgl + (size_t)(j * 8) * 2048, &Ks[0][(w * 16 + j * 8) * 64]);
        gld16(vgl + (size_t)(j * 8) * 2048, &Vs[0][(w * 16 + j * 8) * 64]);
    }
    __syncthreads();

    bf16x8 qb[2][2];
    for (int c = 0; c < 2; ++c) {
        qb[c][0] = *(const bf16x8*)&Ps[(w * 32 + c * 16 + q) * 72 + g8];
        qb[c][1] = *(const bf16x8*)&Ps[(w * 32 + c * 16 + q) * 72 + 32 + g8];
    }

    const int cl0 = ((g) ^ (q & 7)) * 8;
    const int cl1 = ((4 + g) ^ (q & 7)) * 8;

    float li[2] = {0.f, 0.f};
    f32x4 o[2][4] = {};
    const int tmax = 2 * qt + 1;
    const int tdiag = (q0 + w * 32 + 31) >> 6;

    for (int t = 0; t <= tmax; ++t) {
        const int tp = (t < tmax) ? t + 1 : tmax;
        const int nb = (t + 1) & 1;
        for (int j = 0; j < 2; ++j) {
            gld16(kgl + (size_t)(tp * 64 + j * 8) * 2048, &Ks[nb][(w * 16 + j * 8) * 64]);
            gld16(vgl + (size_t)(j * 8) * 2048 + tp * 64, &Vs[nb][(w * 16 + j * 8) * 64]);
        }

        if (t <= tdiag) {
            const int cb0 = t & 1;
            const int kv0 = t * 64;
            const u16* ks = &Ks[cb0][0];
            const u16* vs = &Vs[cb0][0];

            f32x4 st[2][4] = {};
            for (int cb = 0; cb < 4; ++cb) {
                bf16x8 ka0 = *(const bf16x8*)&ks[(cb * 16 + q) * 64 + cl0];
                bf16x8 ka1 = *(const bf16x8*)&ks[(cb * 16 + q) * 64 + cl1];
                st[0][cb] = mfma16(ka0, qb[0][0], st[0][cb]);
                st[1][cb] = mfma16(ka0, qb[1][0], st[1][cb]);
                st[0][cb] = mfma16(ka1, qb[0][1], st[0][cb]);
                st[1][cb] = mfma16(ka1, qb[1][1], st[1][cb]);
            }
            for (int c = 0; c < 2; ++c) {
                if (t == tdiag) {
                    const int qg = q0 + w * 32 + c * 16 + q;
                    for (int cb = 0; cb < 4; ++cb)
                        for (int r = 0; r < 4; ++r) {
                            const int key = kv0 + cb * 16 + g * 4 + r;
                            if (key > qg) st[c][cb][r] = -1e30f;
                        }
                }
                float ps = 0.f;
                for (int cb = 0; cb < 4; ++cb)
                    for (int r = 0; r < 4; ++r) {
                        const float p = __builtin_amdgcn_exp2f(st[c][cb][r]);
                        st[c][cb][r] = p;
                        ps += p;
                    }
                li[c] += ps;
                for (int cb = 0; cb < 4; ++cb) {
                    ushort4 u;
                    u.x = f2b(st[c][cb][0]); u.y = f2b(st[c][cb][1]);
                    u.z = f2b(st[c][cb][2]); u.w = f2b(st[c][cb][3]);
                    *(ushort4*)&Ps[(w * 32 + c * 16 + q) * 72 + cb * 16 + g * 4] = u;
                }
            }
            __builtin_amdgcn_s_waitcnt(0xC07F);  // lgkmcnt(0); DS in-order per wave
            for (int cb = 0; cb < 4; ++cb) {
                bf16x8 va0 = *(const bf16x8*)&vs[(cb * 16 + q) * 64 + cl0];
                bf16x8 va1 = *(const bf16x8*)&vs[(cb * 16 + q) * 64 + cl1];
                bf16x8 pb00 = *(const bf16x8*)&Ps[(w * 32 + q) * 72 + g8];
                bf16x8 pb01 = *(const bf16x8*)&Ps[(w * 32 + q) * 72 + 32 + g8];
                bf16x8 pb10 = *(const bf16x8*)&Ps[(w * 32 + 16 + q) * 72 + g8];
                bf16x8 pb11 = *(const bf16x8*)&Ps[(w * 32 + 16 + q) * 72 + 32 + g8];
                o[0][cb] = mfma16(va0, pb00, o[0][cb]);
                o[1][cb] = mfma16(va0, pb10, o[1][cb]);
                o[0][cb] = mfma16(va1, pb01, o[0][cb]);
                o[1][cb] = mfma16(va1, pb11, o[1][cb]);
            }
        }
        __syncthreads();
    }

    for (int c = 0; c < 2; ++c) {
        float ps = li[c];
        ps += __shfl_xor(ps, 16);
        ps += __shfl_xor(ps, 32);
        const float inv = 1.0f / ps;
        const size_t tok = (size_t)(b * 2048 + q0 + w * 32 + c * 16 + q);
        for (int cb = 0; cb < 4; ++cb) {
            ushort4 u;
            u.x = f2b(o[c][cb][0] * inv); u.y = f2b(o[c][cb][1] * inv);
            u.z = f2b(o[c][cb][2] * inv); u.w = f2b(o[c][cb][3] * inv);
            *(ushort4*)&attn[tok * 1024 + h * 64 + cb * 16 + g * 4] = u;
        }
    }
}

// ---------------------------------------------------------------- launch
extern "C" void kernel_launch(void* const* d_in, const int* in_sizes, int n_in,
                              void* d_out, int out_size, void* d_ws, size_t ws_size,
                              hipStream_t stream) {
    const float* x  = (const float*)d_in[0];
    const float* Wq = (const float*)d_in[1];
    const float* bq = (const float*)d_in[2];
    const float* Wk = (const float*)d_in[3];
    const float* bk = (const float*)d_in[4];
    const float* Wv = (const float*)d_in[5];
    const float* bv = (const float*)d_in[6];
    const float* Wo = (const float*)d_in[7];
    const float* bo = (const float*)d_in[8];
    float* out = (float*)d_out;

    char* ws = (char*)d_ws;
    size_t off = 0;
    auto alloc = [&](size_t bytes) -> void* {
        void* p = ws + off;
        off += (bytes + 255) & ~(size_t)255;
        return p;
    };
    u16*   xb    = (u16*)alloc(8192ull * 1024 * 2);   // x bf16
    u16*   wqkvt = (u16*)alloc(3072ull * 1024 * 2);   // [Wq|Wk|Wv]^T (N,K)
    u16*   wot   = (u16*)alloc(1024ull * 1024 * 2);   // Wo^T
    float* bqkv  = (float*)alloc(3072ull * 4);
    u16*   qk    = (u16*)alloc(8192ull * 2048 * 2);   // [q|k] (token, 2048)
    u16*   vt    = (u16*)alloc(8192ull * 1024 * 2);   // V^T (B,H,Dh,S)
    u16*   attn  = (u16*)alloc(8192ull * 1024 * 2);   // attention out (token, D)

    convert_x<<<8192, 256, 0, stream>>>(x, xb, 8192 * 1024 / 4);
    transpose_w<<<dim3(32, 32, 4), dim3(32, 8), 0, stream>>>(Wq, Wk, Wv, Wo, wqkvt, wot);
    pack_bqkv<<<12, 256, 0, stream>>>(bq, bk, bv, bqkv);
    gemm256<<<dim3(32, 16), 512, 0, stream>>>(xb, wqkvt, bqkv, qk, vt, 1024);
    attn_kernel<<<dim3(64, 16), 256, 0, stream>>>(qk, vt, attn);
    gemm_bt<1><<<dim3(64, 8), 256, 0, stream>>>(attn, wot, bo, out, nullptr, 8192, 1024, 1024, 1024);
}